// Round 3
// baseline (82.775 us; speedup 1.0000x reference)
//
#include <hip/hip_runtime.h>
#include <math.h>

#define DEV __device__ __forceinline__

struct F3 { float x, y, z; };

DEV F3 mkf3(float x, float y, float z){ F3 r; r.x=x; r.y=y; r.z=z; return r; }
DEV F3 f3add(F3 a, F3 b){ return mkf3(a.x+b.x, a.y+b.y, a.z+b.z); }
DEV F3 f3sub(F3 a, F3 b){ return mkf3(a.x-b.x, a.y-b.y, a.z-b.z); }
DEV F3 f3scale(F3 a, float s){ return mkf3(a.x*s, a.y*s, a.z*s); }
DEV float f3dot(F3 a, F3 b){ return a.x*b.x + a.y*b.y + a.z*b.z; }
DEV F3 f3cross(F3 a, F3 b){
  return mkf3(a.y*b.z - a.z*b.y, a.z*b.x - a.x*b.z, a.x*b.y - a.y*b.x);
}
// reference: v / sqrt(max(sum(v*v), 1e-6)); fallback branch is dead
DEV F3 f3dir(F3 v){
  float ss = f3dot(v, v);
  float inv = 1.0f / sqrtf(fmaxf(ss, 1e-6f));
  return f3scale(v, inv);
}
DEV float fast_silu(float x){
  return x * __builtin_amdgcn_rcpf(1.0f + __expf(-x));
}
DEV float fast_sigmoid(float x){
  return __builtin_amdgcn_rcpf(1.0f + __expf(-x));
}

// ---------------------------------------------------------------------------
// Kernel A: per-node frames [N,3,3] + delta_local [N,3]
// ---------------------------------------------------------------------------
__global__ void frames_kernel(const float* __restrict__ xc,
                              const float* __restrict__ xt,
                              float* __restrict__ frames,
                              float* __restrict__ dl, int N)
{
  int n = blockIdx.x * blockDim.x + threadIdx.x;
  if (n >= N) return;
  int pn = (n > 0) ? n - 1 : 0;       // prev = d[max(n-1,0)]
  int qn = (n < N - 1) ? n : N - 2;   // nxt  = d[min(n,N-2)]
  F3 prev = mkf3(xc[(pn+1)*3+0]-xc[pn*3+0], xc[(pn+1)*3+1]-xc[pn*3+1], xc[(pn+1)*3+2]-xc[pn*3+2]);
  F3 nxt  = mkf3(xc[(qn+1)*3+0]-xc[qn*3+0], xc[(qn+1)*3+1]-xc[qn*3+1], xc[(qn+1)*3+2]-xc[qn*3+2]);

  F3 tangent = f3dir(f3add(prev, nxt));
  F3 curv    = f3dir(f3sub(nxt, prev));
  float ct   = f3dot(curv, tangent);
  F3 ay      = f3dir(f3sub(curv, f3scale(tangent, ct)));
  F3 az      = f3dir(f3cross(tangent, ay));
  ay         = f3dir(f3cross(az, tangent));

  float* fr = frames + n * 9;
  fr[0] = tangent.x; fr[1] = ay.x; fr[2] = az.x;
  fr[3] = tangent.y; fr[4] = ay.y; fr[5] = az.y;
  fr[6] = tangent.z; fr[7] = ay.z; fr[8] = az.z;

  F3 delta = mkf3(xt[n*3+0]-xc[n*3+0], xt[n*3+1]-xc[n*3+1], xt[n*3+2]-xc[n*3+2]);
  dl[n*3+0] = f3dot(tangent, delta);
  dl[n*3+1] = f3dot(ay, delta);
  dl[n*3+2] = f3dot(az, delta);
}

// ---------------------------------------------------------------------------
// Kernel B: fused node MLP (layer1 + layer2 + 3 scalar heads), 4 rows/block.
// Transposed float4 activation tiles in LDS; 64-deep W register prefetch.
// ---------------------------------------------------------------------------
__global__ __launch_bounds__(256) void node_mlp(
    const float* __restrict__ h, const float* __restrict__ dl,
    const float* __restrict__ tau,
    const float* __restrict__ W1, const float* __restrict__ b1,
    const float* __restrict__ W2, const float* __restrict__ b2,
    const float* __restrict__ w_src, const float* __restrict__ b_src,
    const float* __restrict__ w_dst, const float* __restrict__ b_dst,
    const float* __restrict__ w_ns, const float* __restrict__ b_ns,
    float* __restrict__ nh, float* __restrict__ srcv,
    float* __restrict__ dstv, float* __restrict__ nsv, int N)
{
  const int n0 = blockIdx.x * 4, tid = threadIdx.x;
  __shared__ float4 fA[262];       // [h, dl, t_emb] transposed, 4 rows
  __shared__ float4 fB[256];       // nh1 transposed, 4 rows
  __shared__ float red[4][4][3];   // [wave][row][head]

  {
    const float* hp = h + n0 * 256 + tid;
    fA[tid] = make_float4(hp[0], hp[256], hp[512], hp[768]);
  }
  if (tid < 6) {
    int k = 256 + tid;
    float4 v;
    if (tid < 3) {
      v = make_float4(dl[(n0+0)*3+tid], dl[(n0+1)*3+tid],
                      dl[(n0+2)*3+tid], dl[(n0+3)*3+tid]);
    } else {
      float t = tau[0];
      float s = (tid == 3) ? t : ((tid == 4) ? sinf(t) : cosf(t));
      v = make_float4(s, s, s, s);
    }
    fA[k] = v;
  }
  __syncthreads();

  // ---- layer 1 ----
  {
    float bb = b1[tid];
    float a0 = bb, a1 = bb, a2 = bb, a3 = bb;
    const float* Wp = W1 + tid;
    for (int kb = 0; kb < 256; kb += 64) {
      float w[64];
      #pragma unroll
      for (int u = 0; u < 64; ++u) w[u] = Wp[(kb + u) * 256];
      #pragma unroll
      for (int u = 0; u < 64; ++u) {
        float4 f = fA[kb + u];
        a0 = fmaf(f.x, w[u], a0); a1 = fmaf(f.y, w[u], a1);
        a2 = fmaf(f.z, w[u], a2); a3 = fmaf(f.w, w[u], a3);
      }
    }
    #pragma unroll
    for (int k = 256; k < 262; ++k) {
      float w = Wp[k * 256];
      float4 f = fA[k];
      a0 = fmaf(f.x, w, a0); a1 = fmaf(f.y, w, a1);
      a2 = fmaf(f.z, w, a2); a3 = fmaf(f.w, w, a3);
    }
    fB[tid] = make_float4(fast_silu(a0), fast_silu(a1), fast_silu(a2), fast_silu(a3));
  }
  __syncthreads();

  // ---- layer 2 + heads ----
  float bb = b2[tid];
  float a0 = bb, a1 = bb, a2 = bb, a3 = bb;
  const float* Wp = W2 + tid;
  for (int kb = 0; kb < 256; kb += 64) {
    float w[64];
    #pragma unroll
    for (int u = 0; u < 64; ++u) w[u] = Wp[(kb + u) * 256];
    #pragma unroll
    for (int u = 0; u < 64; ++u) {
      float4 f = fB[kb + u];
      a0 = fmaf(f.x, w[u], a0); a1 = fmaf(f.y, w[u], a1);
      a2 = fmaf(f.z, w[u], a2); a3 = fmaf(f.w, w[u], a3);
    }
  }

  const float wsv = w_src[tid], wdv = w_dst[tid], wnv = w_ns[tid];
  const int wave = tid >> 6, lane = tid & 63;
  float va[4] = {fast_silu(a0), fast_silu(a1), fast_silu(a2), fast_silu(a3)};
  #pragma unroll
  for (int r = 0; r < 4; ++r) {
    nh[(n0 + r) * 256 + tid] = va[r];
    float ps = va[r] * wsv, pd = va[r] * wdv, pn = va[r] * wnv;
    for (int off = 32; off; off >>= 1) {
      ps += __shfl_down(ps, off);
      pd += __shfl_down(pd, off);
      pn += __shfl_down(pn, off);
    }
    if (lane == 0) { red[wave][r][0] = ps; red[wave][r][1] = pd; red[wave][r][2] = pn; }
  }
  __syncthreads();
  if (tid < 4) {
    int r = tid;
    float s0 = 0.f, s1 = 0.f, s2 = 0.f;
    #pragma unroll
    for (int w = 0; w < 4; ++w) { s0 += red[w][r][0]; s1 += red[w][r][1]; s2 += red[w][r][2]; }
    srcv[n0 + r] = s0 + b_src[0];
    dstv[n0 + r] = s1 + b_dst[0];
    nsv[n0 + r]  = fast_sigmoid(s2 + b_ns[0]);
  }
}

// ---------------------------------------------------------------------------
// Kernel D: fused edge MLP + softmax + aggregation, weights in VGPRs.
// One block (512 thr) per row n. 16 lanes x 8 j per edge, 4 edges/wave-iter.
// Phase 0: stage rel_local/dist + (dst,ns) in LDS.
// Phase 1: logits via register-resident weights + 16-lane butterfly reduce.
// Phase 2: softmax + weighted aggregation.
// ---------------------------------------------------------------------------
__global__ __launch_bounds__(512, 4) void edge_softmax(
    const float* __restrict__ x_t, const float* __restrict__ frames,
    const float* __restrict__ srcv, const float* __restrict__ dstv,
    const float* __restrict__ nsv,
    const float* __restrict__ W_eg1, const float* __restrict__ b_eg1,
    const float* __restrict__ w_eg2, const float* __restrict__ b_eg2,
    float* __restrict__ msgs, int N)
{
  const int n = blockIdx.x, tid = threadIdx.x;
  __shared__ float4 rel4[1024];    // {rl0, rl1, rl2, dist}
  __shared__ float2 dn[1024];      // {dstv[m], nsv[m]}
  __shared__ float  l_s[1024];     // logits
  __shared__ float  redmax[8];
  __shared__ float  red[8][4];

  // frame & center for row n: lane-uniform -> scalar loads
  const float f0 = frames[n*9+0], f1 = frames[n*9+1], f2 = frames[n*9+2],
              f3_ = frames[n*9+3], f4 = frames[n*9+4], f5 = frames[n*9+5],
              f6 = frames[n*9+6], f7 = frames[n*9+7], f8 = frames[n*9+8];
  const float x0 = x_t[n*3+0], x1 = x_t[n*3+1], x2 = x_t[n*3+2];
  const float sn = srcv[n];
  const float b2v = b_eg2[0];

  // ---- phase 0: stage per-m edge geometry ----
  #pragma unroll
  for (int mi = 0; mi < 2; ++mi) {
    const int m = mi * 512 + tid;
    float rx = x_t[m * 3 + 0] - x0;
    float ry = x_t[m * 3 + 1] - x1;
    float rz = x_t[m * 3 + 2] - x2;
    float rl0 = f0 * rx + f3_ * ry + f6 * rz;
    float rl1 = f1 * rx + f4 * ry + f7 * rz;
    float rl2 = f2 * rx + f5 * ry + f8 * rz;
    float dist = sqrtf(rl0 * rl0 + rl1 * rl1 + rl2 * rl2);
    rel4[m] = make_float4(rl0, rl1, rl2, dist);
    dn[m]   = make_float2(dstv[m], nsv[m]);
  }

  // ---- per-lane register weights: j = u*16 + jsub (coalesced) ----
  const int lane = tid & 63, wave = tid >> 6;
  const int jsub = lane & 15;
  const float nl2e = -1.44269504088896340736f;  // -log2(e)
  const float nln2 = -0.69314718055994530942f;  // -ln(2)
  float w0r[8], w1r[8], w2r[8], w3r[8], wbr[8], w2o[8];
  #pragma unroll
  for (int u = 0; u < 8; ++u) {
    int j = u * 16 + jsub;
    w0r[u] = nl2e * W_eg1[j];
    w1r[u] = nl2e * W_eg1[128 + j];
    w2r[u] = nl2e * W_eg1[256 + j];
    w3r[u] = nl2e * W_eg1[384 + j];
    wbr[u] = nl2e * b_eg1[j];
    w2o[u] = nln2 * w_eg2[j];
  }
  __syncthreads();

  // ---- phase 1: logits. wave handles edges [wave*128, wave*128+128) ----
  float lmax = -3.4e38f;
  const int grp = lane >> 4;
  for (int i = 0; i < 32; ++i) {
    const int m = wave * 128 + i * 4 + grp;
    float4 rd = rel4[m];                       // broadcast within 16-lane group
    float acc = 0.f;
    #pragma unroll
    for (int u = 0; u < 8; ++u) {
      // tp = -log2e * (W.r + b);  exp2(tp) = exp(-t)
      float tp = fmaf(w0r[u], rd.x, fmaf(w1r[u], rd.y,
                 fmaf(w2r[u], rd.z, fmaf(w3r[u], rd.w, wbr[u]))));
      float e  = __builtin_amdgcn_exp2f(tp);
      float sg = __builtin_amdgcn_rcpf(1.0f + e);   // sigma(t)
      acc = fmaf(w2o[u], tp * sg, acc);             // w2 * t * sigma(t)
    }
    #pragma unroll
    for (int mask = 1; mask < 16; mask <<= 1) acc += __shfl_xor(acc, mask);
    float lg = sn + dn[m].x + b2v + acc;
    if (m == n) lg = -10000.0f;
    lmax = fmaxf(lmax, lg);
    if (jsub == 0) l_s[m] = lg;
  }

  // ---- block max reduce ----
  for (int off = 32; off; off >>= 1) lmax = fmaxf(lmax, __shfl_down(lmax, off));
  if (lane == 0) redmax[wave] = lmax;
  __syncthreads();
  float mx = redmax[0];
  #pragma unroll
  for (int w = 1; w < 8; ++w) mx = fmaxf(mx, redmax[w]);

  // ---- phase 2: softmax + aggregation ----
  float sum = 0.f, a0 = 0.f, a1 = 0.f, a2 = 0.f;
  #pragma unroll
  for (int mi = 0; mi < 2; ++mi) {
    const int m = mi * 512 + tid;
    float4 rd = rel4[m];
    float e = __expf(l_s[m] - mx);    // diag underflows to 0
    sum += e;
    float w = e * dn[m].y;
    a0 = fmaf(w, rd.x, a0);
    a1 = fmaf(w, rd.y, a1);
    a2 = fmaf(w, rd.z, a2);
  }
  for (int off = 32; off; off >>= 1) {
    sum += __shfl_down(sum, off);
    a0 += __shfl_down(a0, off);
    a1 += __shfl_down(a1, off);
    a2 += __shfl_down(a2, off);
  }
  if (lane == 0) { red[wave][0] = sum; red[wave][1] = a0; red[wave][2] = a1; red[wave][3] = a2; }
  __syncthreads();
  if (tid == 0) {
    float Z = 0.f, m0 = 0.f, m1 = 0.f, m2 = 0.f;
    #pragma unroll
    for (int w = 0; w < 8; ++w) {
      Z += red[w][0]; m0 += red[w][1]; m1 += red[w][2]; m2 += red[w][3];
    }
    float invZ = 1.0f / Z;
    msgs[n * 3 + 0] = m0 * invZ;
    msgs[n * 3 + 1] = m1 * invZ;
    msgs[n * 3 + 2] = m2 * invZ;
  }
}

// ---------------------------------------------------------------------------
// Kernel E: out MLP + 0.25*msgs + frame rotation
// ---------------------------------------------------------------------------
__global__ __launch_bounds__(256) void out_mlp(
    const float* __restrict__ nh, const float* __restrict__ dl,
    const float* __restrict__ msgs, const float* __restrict__ frames,
    const float* __restrict__ W1, const float* __restrict__ b1,
    const float* __restrict__ W2, const float* __restrict__ b2,
    float* __restrict__ out, int N)
{
  const int n0 = blockIdx.x * 4, tid = threadIdx.x;
  __shared__ float4 feat4[262];
  __shared__ float red[4][4][3];
  {
    const float* hp = nh + n0 * 256 + tid;
    feat4[tid] = make_float4(hp[0], hp[256], hp[512], hp[768]);
  }
  if (tid < 6) {
    int k = 256 + tid;
    float4 v;
    if (tid < 3) {
      v = make_float4(dl[(n0+0)*3+tid], dl[(n0+1)*3+tid],
                      dl[(n0+2)*3+tid], dl[(n0+3)*3+tid]);
    } else {
      int c = tid - 3;
      v = make_float4(msgs[(n0+0)*3+c], msgs[(n0+1)*3+c],
                      msgs[(n0+2)*3+c], msgs[(n0+3)*3+c]);
    }
    feat4[k] = v;
  }
  __syncthreads();

  float bb = b1[tid];
  float a0 = bb, a1 = bb, a2 = bb, a3 = bb;
  const float* Wp = W1 + tid;
  for (int kb = 0; kb < 256; kb += 64) {
    float w[64];
    #pragma unroll
    for (int u = 0; u < 64; ++u) w[u] = Wp[(kb + u) * 256];
    #pragma unroll
    for (int u = 0; u < 64; ++u) {
      float4 f = feat4[kb + u];
      a0 = fmaf(f.x, w[u], a0); a1 = fmaf(f.y, w[u], a1);
      a2 = fmaf(f.z, w[u], a2); a3 = fmaf(f.w, w[u], a3);
    }
  }
  #pragma unroll
  for (int k = 256; k < 262; ++k) {
    float w = Wp[k * 256];
    float4 f = feat4[k];
    a0 = fmaf(f.x, w, a0); a1 = fmaf(f.y, w, a1);
    a2 = fmaf(f.z, w, a2); a3 = fmaf(f.w, w, a3);
  }

  const float w0 = W2[tid * 3 + 0], w1 = W2[tid * 3 + 1], w2 = W2[tid * 3 + 2];
  const int wave = tid >> 6, lane = tid & 63;
  float va[4] = {fast_silu(a0), fast_silu(a1), fast_silu(a2), fast_silu(a3)};
  #pragma unroll
  for (int r = 0; r < 4; ++r) {
    float p0 = va[r] * w0, p1 = va[r] * w1, p2 = va[r] * w2;
    for (int off = 32; off; off >>= 1) {
      p0 += __shfl_down(p0, off);
      p1 += __shfl_down(p1, off);
      p2 += __shfl_down(p2, off);
    }
    if (lane == 0) { red[wave][r][0] = p0; red[wave][r][1] = p1; red[wave][r][2] = p2; }
  }
  __syncthreads();
  if (tid < 4) {
    int r = tid, n = n0 + r;
    float s0 = 0.f, s1 = 0.f, s2 = 0.f;
    #pragma unroll
    for (int w = 0; w < 4; ++w) { s0 += red[w][r][0]; s1 += red[w][r][1]; s2 += red[w][r][2]; }
    float m0 = msgs[n * 3 + 0], m1 = msgs[n * 3 + 1], m2 = msgs[n * 3 + 2];
    float v0 = s0 + b2[0] + 0.25f * m0;
    float v1 = s1 + b2[1] + 0.25f * m1;
    float v2 = s2 + b2[2] + 0.25f * m2;
    const float* fr = frames + n * 9;
    out[n * 3 + 0] = fr[0] * v0 + fr[1] * v1 + fr[2] * v2;
    out[n * 3 + 1] = fr[3] * v0 + fr[4] * v1 + fr[5] * v2;
    out[n * 3 + 2] = fr[6] * v0 + fr[7] * v1 + fr[8] * v2;
  }
}

// ---------------------------------------------------------------------------
extern "C" void kernel_launch(void* const* d_in, const int* in_sizes, int n_in,
                              void* d_out, int out_size, void* d_ws, size_t ws_size,
                              hipStream_t stream) {
  const float* h      = (const float*)d_in[0];
  const float* x_t    = (const float*)d_in[1];
  const float* x_cond = (const float*)d_in[2];
  const float* tau    = (const float*)d_in[3];
  const float* W_np1  = (const float*)d_in[4];
  const float* b_np1  = (const float*)d_in[5];
  const float* W_np2  = (const float*)d_in[6];
  const float* b_np2  = (const float*)d_in[7];
  const float* w_src  = (const float*)d_in[8];
  const float* b_src  = (const float*)d_in[9];
  const float* w_dst  = (const float*)d_in[10];
  const float* b_dst  = (const float*)d_in[11];
  const float* w_ns   = (const float*)d_in[12];
  const float* b_ns   = (const float*)d_in[13];
  const float* W_eg1  = (const float*)d_in[14];
  const float* b_eg1  = (const float*)d_in[15];
  const float* w_eg2  = (const float*)d_in[16];
  const float* b_eg2  = (const float*)d_in[17];
  const float* W_out1 = (const float*)d_in[18];
  const float* b_out1 = (const float*)d_in[19];
  const float* W_out2 = (const float*)d_in[20];
  const float* b_out2 = (const float*)d_in[21];
  float* out = (float*)d_out;

  const int N = in_sizes[1] / 3;  // 1024

  float* ws     = (float*)d_ws;
  float* frames = ws;                 // N*9
  float* dl     = frames + N * 9;     // N*3
  float* nh     = dl + N * 3;         // N*256
  float* srcv   = nh + N * 256;       // N
  float* dstv   = srcv + N;           // N
  float* nsv    = dstv + N;           // N
  float* msgs   = nsv + N;            // N*3

  frames_kernel<<<(N + 255) / 256, 256, 0, stream>>>(x_cond, x_t, frames, dl, N);
  node_mlp<<<N / 4, 256, 0, stream>>>(h, dl, tau, W_np1, b_np1, W_np2, b_np2,
                                      w_src, b_src, w_dst, b_dst, w_ns, b_ns,
                                      nh, srcv, dstv, nsv, N);
  edge_softmax<<<N, 512, 0, stream>>>(x_t, frames, srcv, dstv, nsv,
                                      W_eg1, b_eg1, w_eg2, b_eg2, msgs, N);
  out_mlp<<<N / 4, 256, 0, stream>>>(nh, dl, msgs, frames,
                                     W_out1, b_out1, W_out2, b_out2, out, N);
}

// Round 4
// 66.290 us; speedup vs baseline: 1.2487x; 1.2487x over previous
//
#include <hip/hip_runtime.h>
#include <math.h>

#define DEV __device__ __forceinline__

struct F3 { float x, y, z; };

DEV F3 mkf3(float x, float y, float z){ F3 r; r.x=x; r.y=y; r.z=z; return r; }
DEV F3 f3add(F3 a, F3 b){ return mkf3(a.x+b.x, a.y+b.y, a.z+b.z); }
DEV F3 f3sub(F3 a, F3 b){ return mkf3(a.x-b.x, a.y-b.y, a.z-b.z); }
DEV F3 f3scale(F3 a, float s){ return mkf3(a.x*s, a.y*s, a.z*s); }
DEV float f3dot(F3 a, F3 b){ return a.x*b.x + a.y*b.y + a.z*b.z; }
DEV F3 f3cross(F3 a, F3 b){
  return mkf3(a.y*b.z - a.z*b.y, a.z*b.x - a.x*b.z, a.x*b.y - a.y*b.x);
}
// reference: v / sqrt(max(sum(v*v), 1e-6)); fallback branch is dead
DEV F3 f3dir(F3 v){
  float ss = f3dot(v, v);
  float inv = 1.0f / sqrtf(fmaxf(ss, 1e-6f));
  return f3scale(v, inv);
}
DEV float fast_silu(float x){
  return x * __builtin_amdgcn_rcpf(1.0f + __expf(-x));
}
DEV float fast_sigmoid(float x){
  return __builtin_amdgcn_rcpf(1.0f + __expf(-x));
}

// ---------------------------------------------------------------------------
// Kernel A: per-node frames [N,3,3] + delta_local [N,3]
// ---------------------------------------------------------------------------
__global__ void frames_kernel(const float* __restrict__ xc,
                              const float* __restrict__ xt,
                              float* __restrict__ frames,
                              float* __restrict__ dl, int N)
{
  int n = blockIdx.x * blockDim.x + threadIdx.x;
  if (n >= N) return;
  int pn = (n > 0) ? n - 1 : 0;       // prev = d[max(n-1,0)]
  int qn = (n < N - 1) ? n : N - 2;   // nxt  = d[min(n,N-2)]
  F3 prev = mkf3(xc[(pn+1)*3+0]-xc[pn*3+0], xc[(pn+1)*3+1]-xc[pn*3+1], xc[(pn+1)*3+2]-xc[pn*3+2]);
  F3 nxt  = mkf3(xc[(qn+1)*3+0]-xc[qn*3+0], xc[(qn+1)*3+1]-xc[qn*3+1], xc[(qn+1)*3+2]-xc[qn*3+2]);

  F3 tangent = f3dir(f3add(prev, nxt));
  F3 curv    = f3dir(f3sub(nxt, prev));
  float ct   = f3dot(curv, tangent);
  F3 ay      = f3dir(f3sub(curv, f3scale(tangent, ct)));
  F3 az      = f3dir(f3cross(tangent, ay));
  ay         = f3dir(f3cross(az, tangent));

  float* fr = frames + n * 9;
  fr[0] = tangent.x; fr[1] = ay.x; fr[2] = az.x;
  fr[3] = tangent.y; fr[4] = ay.y; fr[5] = az.y;
  fr[6] = tangent.z; fr[7] = ay.z; fr[8] = az.z;

  F3 delta = mkf3(xt[n*3+0]-xc[n*3+0], xt[n*3+1]-xc[n*3+1], xt[n*3+2]-xc[n*3+2]);
  dl[n*3+0] = f3dot(tangent, delta);
  dl[n*3+1] = f3dot(ay, delta);
  dl[n*3+2] = f3dot(az, delta);
}

// ---------------------------------------------------------------------------
// Kernel B: fused node MLP (layer1 + layer2 + 3 scalar heads), 4 rows/block.
// ---------------------------------------------------------------------------
__global__ __launch_bounds__(256) void node_mlp(
    const float* __restrict__ h, const float* __restrict__ dl,
    const float* __restrict__ tau,
    const float* __restrict__ W1, const float* __restrict__ b1,
    const float* __restrict__ W2, const float* __restrict__ b2,
    const float* __restrict__ w_src, const float* __restrict__ b_src,
    const float* __restrict__ w_dst, const float* __restrict__ b_dst,
    const float* __restrict__ w_ns, const float* __restrict__ b_ns,
    float* __restrict__ nh, float* __restrict__ srcv,
    float* __restrict__ dstv, float* __restrict__ nsv, int N)
{
  const int n0 = blockIdx.x * 4, tid = threadIdx.x;
  __shared__ float4 fA[262];       // [h, dl, t_emb] transposed, 4 rows
  __shared__ float4 fB[256];       // nh1 transposed, 4 rows
  __shared__ float red[4][4][3];   // [wave][row][head]

  {
    const float* hp = h + n0 * 256 + tid;
    fA[tid] = make_float4(hp[0], hp[256], hp[512], hp[768]);
  }
  if (tid < 6) {
    int k = 256 + tid;
    float4 v;
    if (tid < 3) {
      v = make_float4(dl[(n0+0)*3+tid], dl[(n0+1)*3+tid],
                      dl[(n0+2)*3+tid], dl[(n0+3)*3+tid]);
    } else {
      float t = tau[0];
      float s = (tid == 3) ? t : ((tid == 4) ? sinf(t) : cosf(t));
      v = make_float4(s, s, s, s);
    }
    fA[k] = v;
  }
  __syncthreads();

  // ---- layer 1 ----
  {
    float bb = b1[tid];
    float a0 = bb, a1 = bb, a2 = bb, a3 = bb;
    const float* Wp = W1 + tid;
    for (int kb = 0; kb < 256; kb += 64) {
      float w[64];
      #pragma unroll
      for (int u = 0; u < 64; ++u) w[u] = Wp[(kb + u) * 256];
      #pragma unroll
      for (int u = 0; u < 64; ++u) {
        float4 f = fA[kb + u];
        a0 = fmaf(f.x, w[u], a0); a1 = fmaf(f.y, w[u], a1);
        a2 = fmaf(f.z, w[u], a2); a3 = fmaf(f.w, w[u], a3);
      }
    }
    #pragma unroll
    for (int k = 256; k < 262; ++k) {
      float w = Wp[k * 256];
      float4 f = fA[k];
      a0 = fmaf(f.x, w, a0); a1 = fmaf(f.y, w, a1);
      a2 = fmaf(f.z, w, a2); a3 = fmaf(f.w, w, a3);
    }
    fB[tid] = make_float4(fast_silu(a0), fast_silu(a1), fast_silu(a2), fast_silu(a3));
  }
  __syncthreads();

  // ---- layer 2 + heads ----
  float bb = b2[tid];
  float a0 = bb, a1 = bb, a2 = bb, a3 = bb;
  const float* Wp = W2 + tid;
  for (int kb = 0; kb < 256; kb += 64) {
    float w[64];
    #pragma unroll
    for (int u = 0; u < 64; ++u) w[u] = Wp[(kb + u) * 256];
    #pragma unroll
    for (int u = 0; u < 64; ++u) {
      float4 f = fB[kb + u];
      a0 = fmaf(f.x, w[u], a0); a1 = fmaf(f.y, w[u], a1);
      a2 = fmaf(f.z, w[u], a2); a3 = fmaf(f.w, w[u], a3);
    }
  }

  const float wsv = w_src[tid], wdv = w_dst[tid], wnv = w_ns[tid];
  const int wave = tid >> 6, lane = tid & 63;
  float va[4] = {fast_silu(a0), fast_silu(a1), fast_silu(a2), fast_silu(a3)};
  #pragma unroll
  for (int r = 0; r < 4; ++r) {
    nh[(n0 + r) * 256 + tid] = va[r];
    float ps = va[r] * wsv, pd = va[r] * wdv, pn = va[r] * wnv;
    for (int off = 32; off; off >>= 1) {
      ps += __shfl_down(ps, off);
      pd += __shfl_down(pd, off);
      pn += __shfl_down(pn, off);
    }
    if (lane == 0) { red[wave][r][0] = ps; red[wave][r][1] = pd; red[wave][r][2] = pn; }
  }
  __syncthreads();
  if (tid < 4) {
    int r = tid;
    float s0 = 0.f, s1 = 0.f, s2 = 0.f;
    #pragma unroll
    for (int w = 0; w < 4; ++w) { s0 += red[w][r][0]; s1 += red[w][r][1]; s2 += red[w][r][2]; }
    srcv[n0 + r] = s0 + b_src[0];
    dstv[n0 + r] = s1 + b_dst[0];
    nsv[n0 + r]  = fast_sigmoid(s2 + b_ns[0]);
  }
}

// ---------------------------------------------------------------------------
// Kernel D: fused edge MLP + softmax + aggregation.
// One block (256 thr, 4 waves) per row n; each thread owns 4 edges, all
// processed interleaved in one j-loop. Weights are wave-uniform -> the
// compiler keeps them in SGPRs (s_load); the inner loop has ZERO LDS ops.
// -log2e is folded into the per-edge inputs; phase 2 recovers raw rel via
// * (-ln2) (exact inverse).
// ---------------------------------------------------------------------------
__global__ __launch_bounds__(256, 8) void edge_softmax(
    const float* __restrict__ x_t, const float* __restrict__ frames,
    const float* __restrict__ srcv, const float* __restrict__ dstv,
    const float* __restrict__ nsv,
    const float* __restrict__ W_eg1, const float* __restrict__ b_eg1,
    const float* __restrict__ w_eg2, const float* __restrict__ b_eg2,
    float* __restrict__ msgs, int N)
{
  const int n = blockIdx.x, tid = threadIdx.x;
  __shared__ float redmax[4];
  __shared__ float red[4][4];

  // row-uniform data -> scalar loads
  const float f0 = frames[n*9+0], f1 = frames[n*9+1], f2 = frames[n*9+2],
              f3_ = frames[n*9+3], f4 = frames[n*9+4], f5 = frames[n*9+5],
              f6 = frames[n*9+6], f7 = frames[n*9+7], f8 = frames[n*9+8];
  const float x0 = x_t[n*3+0], x1 = x_t[n*3+1], x2 = x_t[n*3+2];
  const float sn = srcv[n];
  const float b2v = b_eg2[0];

  const float nl2e = -1.44269504088896340736f;  // -log2(e)
  const float nln2 = -0.69314718055994530942f;  // -ln(2);  nl2e*nln2 == 1

  // ---- phase 0: per-edge rel_local, pre-scaled by -log2e ----
  float ds0[4], ds1[4], ds2[4], ds3[4];
  #pragma unroll
  for (int e = 0; e < 4; ++e) {
    const int m = e * 256 + tid;
    float rx = x_t[m * 3 + 0] - x0;
    float ry = x_t[m * 3 + 1] - x1;
    float rz = x_t[m * 3 + 2] - x2;
    float rl0 = f0 * rx + f3_ * ry + f6 * rz;
    float rl1 = f1 * rx + f4 * ry + f7 * rz;
    float rl2 = f2 * rx + f5 * ry + f8 * rz;
    float dist = sqrtf(rl0 * rl0 + rl1 * rl1 + rl2 * rl2);
    ds0[e] = nl2e * rl0; ds1[e] = nl2e * rl1;
    ds2[e] = nl2e * rl2; ds3[e] = nl2e * dist;
  }

  // ---- phase 1: edge-MLP logits, weights via SGPR ----
  float acc[4] = {0.f, 0.f, 0.f, 0.f};
  #pragma unroll 8
  for (int j = 0; j < 128; ++j) {
    const float wx = W_eg1[j];          // uniform -> s_load
    const float wy = W_eg1[128 + j];
    const float wz = W_eg1[256 + j];
    const float wd = W_eg1[384 + j];
    const float bj = b_eg1[j];
    const float w2 = w_eg2[j];
    const float bs = bj * nl2e;         // v_mul s, v(nl2e)
    #pragma unroll
    for (int e = 0; e < 4; ++e) {
      // tp = -log2e * (W.r + b);  exp2(tp) = exp(-t);  tp*(-ln2) = t... folded
      float tp = fmaf(wd, ds3[e], bs);
      tp = fmaf(wz, ds2[e], tp);
      tp = fmaf(wy, ds1[e], tp);
      tp = fmaf(wx, ds0[e], tp);
      float ex = __builtin_amdgcn_exp2f(tp);
      float sg = __builtin_amdgcn_rcpf(1.0f + ex);   // sigma(t)
      acc[e] = fmaf(w2, tp * sg, acc[e]);            // w2 * tp * sigma; *(-ln2) later
    }
  }

  float l[4];
  float lmax = -3.4e38f;
  #pragma unroll
  for (int e = 0; e < 4; ++e) {
    const int m = e * 256 + tid;
    float lg = sn + dstv[m] + b2v + nln2 * acc[e];
    if (m == n) lg = -10000.0f;
    l[e] = lg;
    lmax = fmaxf(lmax, lg);
  }

  // ---- block max reduce (4 waves) ----
  for (int off = 32; off; off >>= 1) lmax = fmaxf(lmax, __shfl_down(lmax, off));
  const int wave = tid >> 6, lane = tid & 63;
  if (lane == 0) redmax[wave] = lmax;
  __syncthreads();
  const float mx = fmaxf(fmaxf(redmax[0], redmax[1]), fmaxf(redmax[2], redmax[3]));

  // ---- phase 2: softmax + aggregation (recover rel via *(-ln2)) ----
  float sum = 0.f, a0 = 0.f, a1 = 0.f, a2 = 0.f;
  #pragma unroll
  for (int e = 0; e < 4; ++e) {
    const int m = e * 256 + tid;
    float ee = __expf(l[e] - mx);     // diag underflows to 0
    sum += ee;
    float w = ee * nsv[m];
    a0 = fmaf(w, ds0[e] * nln2, a0);
    a1 = fmaf(w, ds1[e] * nln2, a1);
    a2 = fmaf(w, ds2[e] * nln2, a2);
  }
  for (int off = 32; off; off >>= 1) {
    sum += __shfl_down(sum, off);
    a0 += __shfl_down(a0, off);
    a1 += __shfl_down(a1, off);
    a2 += __shfl_down(a2, off);
  }
  if (lane == 0) { red[wave][0] = sum; red[wave][1] = a0; red[wave][2] = a1; red[wave][3] = a2; }
  __syncthreads();
  if (tid == 0) {
    float Z = red[0][0] + red[1][0] + red[2][0] + red[3][0];
    float m0 = red[0][1] + red[1][1] + red[2][1] + red[3][1];
    float m1 = red[0][2] + red[1][2] + red[2][2] + red[3][2];
    float m2 = red[0][3] + red[1][3] + red[2][3] + red[3][3];
    float invZ = 1.0f / Z;
    msgs[n * 3 + 0] = m0 * invZ;
    msgs[n * 3 + 1] = m1 * invZ;
    msgs[n * 3 + 2] = m2 * invZ;
  }
}

// ---------------------------------------------------------------------------
// Kernel E: out MLP + 0.25*msgs + frame rotation
// ---------------------------------------------------------------------------
__global__ __launch_bounds__(256) void out_mlp(
    const float* __restrict__ nh, const float* __restrict__ dl,
    const float* __restrict__ msgs, const float* __restrict__ frames,
    const float* __restrict__ W1, const float* __restrict__ b1,
    const float* __restrict__ W2, const float* __restrict__ b2,
    float* __restrict__ out, int N)
{
  const int n0 = blockIdx.x * 4, tid = threadIdx.x;
  __shared__ float4 feat4[262];
  __shared__ float red[4][4][3];
  {
    const float* hp = nh + n0 * 256 + tid;
    feat4[tid] = make_float4(hp[0], hp[256], hp[512], hp[768]);
  }
  if (tid < 6) {
    int k = 256 + tid;
    float4 v;
    if (tid < 3) {
      v = make_float4(dl[(n0+0)*3+tid], dl[(n0+1)*3+tid],
                      dl[(n0+2)*3+tid], dl[(n0+3)*3+tid]);
    } else {
      int c = tid - 3;
      v = make_float4(msgs[(n0+0)*3+c], msgs[(n0+1)*3+c],
                      msgs[(n0+2)*3+c], msgs[(n0+3)*3+c]);
    }
    feat4[k] = v;
  }
  __syncthreads();

  float bb = b1[tid];
  float a0 = bb, a1 = bb, a2 = bb, a3 = bb;
  const float* Wp = W1 + tid;
  for (int kb = 0; kb < 256; kb += 64) {
    float w[64];
    #pragma unroll
    for (int u = 0; u < 64; ++u) w[u] = Wp[(kb + u) * 256];
    #pragma unroll
    for (int u = 0; u < 64; ++u) {
      float4 f = feat4[kb + u];
      a0 = fmaf(f.x, w[u], a0); a1 = fmaf(f.y, w[u], a1);
      a2 = fmaf(f.z, w[u], a2); a3 = fmaf(f.w, w[u], a3);
    }
  }
  #pragma unroll
  for (int k = 256; k < 262; ++k) {
    float w = Wp[k * 256];
    float4 f = feat4[k];
    a0 = fmaf(f.x, w, a0); a1 = fmaf(f.y, w, a1);
    a2 = fmaf(f.z, w, a2); a3 = fmaf(f.w, w, a3);
  }

  const float w0 = W2[tid * 3 + 0], w1 = W2[tid * 3 + 1], w2 = W2[tid * 3 + 2];
  const int wave = tid >> 6, lane = tid & 63;
  float va[4] = {fast_silu(a0), fast_silu(a1), fast_silu(a2), fast_silu(a3)};
  #pragma unroll
  for (int r = 0; r < 4; ++r) {
    float p0 = va[r] * w0, p1 = va[r] * w1, p2 = va[r] * w2;
    for (int off = 32; off; off >>= 1) {
      p0 += __shfl_down(p0, off);
      p1 += __shfl_down(p1, off);
      p2 += __shfl_down(p2, off);
    }
    if (lane == 0) { red[wave][r][0] = p0; red[wave][r][1] = p1; red[wave][r][2] = p2; }
  }
  __syncthreads();
  if (tid < 4) {
    int r = tid, n = n0 + r;
    float s0 = 0.f, s1 = 0.f, s2 = 0.f;
    #pragma unroll
    for (int w = 0; w < 4; ++w) { s0 += red[w][r][0]; s1 += red[w][r][1]; s2 += red[w][r][2]; }
    float m0 = msgs[n * 3 + 0], m1 = msgs[n * 3 + 1], m2 = msgs[n * 3 + 2];
    float v0 = s0 + b2[0] + 0.25f * m0;
    float v1 = s1 + b2[1] + 0.25f * m1;
    float v2 = s2 + b2[2] + 0.25f * m2;
    const float* fr = frames + n * 9;
    out[n * 3 + 0] = fr[0] * v0 + fr[1] * v1 + fr[2] * v2;
    out[n * 3 + 1] = fr[3] * v0 + fr[4] * v1 + fr[5] * v2;
    out[n * 3 + 2] = fr[6] * v0 + fr[7] * v1 + fr[8] * v2;
  }
}

// ---------------------------------------------------------------------------
extern "C" void kernel_launch(void* const* d_in, const int* in_sizes, int n_in,
                              void* d_out, int out_size, void* d_ws, size_t ws_size,
                              hipStream_t stream) {
  const float* h      = (const float*)d_in[0];
  const float* x_t    = (const float*)d_in[1];
  const float* x_cond = (const float*)d_in[2];
  const float* tau    = (const float*)d_in[3];
  const float* W_np1  = (const float*)d_in[4];
  const float* b_np1  = (const float*)d_in[5];
  const float* W_np2  = (const float*)d_in[6];
  const float* b_np2  = (const float*)d_in[7];
  const float* w_src  = (const float*)d_in[8];
  const float* b_src  = (const float*)d_in[9];
  const float* w_dst  = (const float*)d_in[10];
  const float* b_dst  = (const float*)d_in[11];
  const float* w_ns   = (const float*)d_in[12];
  const float* b_ns   = (const float*)d_in[13];
  const float* W_eg1  = (const float*)d_in[14];
  const float* b_eg1  = (const float*)d_in[15];
  const float* w_eg2  = (const float*)d_in[16];
  const float* b_eg2  = (const float*)d_in[17];
  const float* W_out1 = (const float*)d_in[18];
  const float* b_out1 = (const float*)d_in[19];
  const float* W_out2 = (const float*)d_in[20];
  const float* b_out2 = (const float*)d_in[21];
  float* out = (float*)d_out;

  const int N = in_sizes[1] / 3;  // 1024

  float* ws     = (float*)d_ws;
  float* frames = ws;                 // N*9
  float* dl     = frames + N * 9;     // N*3
  float* nh     = dl + N * 3;         // N*256
  float* srcv   = nh + N * 256;       // N
  float* dstv   = srcv + N;           // N
  float* nsv    = dstv + N;           // N
  float* msgs   = nsv + N;            // N*3

  frames_kernel<<<(N + 255) / 256, 256, 0, stream>>>(x_cond, x_t, frames, dl, N);
  node_mlp<<<N / 4, 256, 0, stream>>>(h, dl, tau, W_np1, b_np1, W_np2, b_np2,
                                      w_src, b_src, w_dst, b_dst, w_ns, b_ns,
                                      nh, srcv, dstv, nsv, N);
  edge_softmax<<<N, 256, 0, stream>>>(x_t, frames, srcv, dstv, nsv,
                                      W_eg1, b_eg1, w_eg2, b_eg2, msgs, N);
  out_mlp<<<N / 4, 256, 0, stream>>>(nh, dl, msgs, frames,
                                     W_out1, b_out1, W_out2, b_out2, out, N);
}